// Round 5
// baseline (505.901 us; speedup 1.0000x reference)
//
#include <hip/hip_runtime.h>
#include <cstdint>
#include <cstddef>

#define BB 32
#define SS 4096
#define DD 512
#define AA 3
#define KK 4
#define OUTD 512

#define NCHUNK 64
#define ROWS_PER_BLOCK (SS / NCHUNK)        // 64
#define ROWS_PER_WAVE  (ROWS_PER_BLOCK / 4) // 16
#define GROUPS 8                            // rows processed per wave-iteration
#define NITER (ROWS_PER_WAVE / GROUPS)      // 2

// Small-weights LDS layout (sw):
// [0..11]  centers (K*A=12), [12..14] ba, [15..32] Wh ([a][i] at 15+a*6+i),
// [33..38] bh, [39..62] Wk ([i][k] at 39+i*4+k), [63..66] bk
//
// R4 lesson: one-row-per-wave = 64-lane butterfly (6 shuffle levels ~200 cyc
// serial) + 64-lane-redundant softmax (~100 wave-inst) PER ROW -> ~230
// wave-inst/row vs 56 FMA floor; plus wa_lds reads at d0=8*lane were 16-way
// bank-conflicted (3.34M conflict cycles). Nothing saturated: latency-bound.
// R5: 8-lane row groups. g=lane>>3 picks one of 8 concurrent rows, c=lane&7.
//  - af: d = m*32 + c*4 -> contiguous 128B per group per instr (coalesced);
//    waT[a][d] LDS reads: 8 bank-quads, same-address broadcast within quad
//    -> conflict-free with NO padding.
//  - butterfly: xor 1,2,4 only (3 levels, amortized over 8 rows).
//  - softmax: each lane does its own row -> 8x less redundant wave work.
//  - pooling: lane owns d in {4l..4l+3} u {256+4l..+3} -> both loads are
//    contiguous 1KB/instr; x re-read is L2-hot (touched in af moments ago).
__global__ __launch_bounds__(256) void fused_pool_kernel(
    const float* __restrict__ x, const float* __restrict__ centers,
    const float* __restrict__ Wa, const float* __restrict__ ba,
    const float* __restrict__ Wh, const float* __restrict__ bh,
    const float* __restrict__ Wk, const float* __restrict__ bk,
    float* __restrict__ pooled)
{
    __shared__ float  sw[68];
    __shared__ float  waT[AA * DD];        // 6 KB, [a][d] transposed
    __shared__ float4 fw_lds[4 * GROUPS];  // [wave][g] -> fw[4]
    __shared__ float  red[KK * DD];        // 8 KB block-shared partial

    const int tid  = threadIdx.x;
    const int wave = tid >> 6;
    const int lane = tid & 63;
    const int g    = lane >> 3;            // row-in-group
    const int c    = lane & 7;             // slot within 8-lane group
    const int b     = blockIdx.y;
    const int chunk = blockIdx.x;

    if (tid < 12)      sw[tid] = centers[tid];
    else if (tid < 15) sw[tid] = ba[tid - 12];
    else if (tid < 33) sw[tid] = Wh[tid - 15];
    else if (tid < 39) sw[tid] = bh[tid - 33];
    else if (tid < 63) sw[tid] = Wk[tid - 39];
    else if (tid < 67) sw[tid] = bk[tid - 63];
    // Wa is [d][a] row-major; stage transposed as waT[a][d]
    for (int i = tid; i < AA * DD; i += 256) {
        int d = i / 3, a = i - 3 * d;
        waT[a * DD + d] = Wa[i];
    }
    for (int i = tid; i < KK * DD; i += 256) red[i] = 0.0f;
    __syncthreads();

    const int s_base = chunk * ROWS_PER_BLOCK + wave * ROWS_PER_WAVE;
    const float* xbase = x + (size_t)b * SS * DD;

    float acc[KK][8];
    #pragma unroll
    for (int k = 0; k < KK; ++k)
        #pragma unroll
        for (int j = 0; j < 8; ++j) acc[k][j] = 0.0f;

    #pragma unroll 1
    for (int t = 0; t < NITER; ++t) {
        const int s0 = s_base + t * GROUPS;

        // ---- af phase: this lane covers 64 d's of row (s0+g) ----
        {
            const float* xg = xbase + (size_t)(s0 + g) * DD + c * 4;
            float p0 = 0.f, p1 = 0.f, p2 = 0.f;
            #pragma unroll 4
            for (int m = 0; m < 16; ++m) {
                const int d = m * 32;
                float4 xv = *(const float4*)(xg + d);
                float4 w0 = *(const float4*)(waT + 0 * DD + d + c * 4);
                float4 w1 = *(const float4*)(waT + 1 * DD + d + c * 4);
                float4 w2 = *(const float4*)(waT + 2 * DD + d + c * 4);
                p0 += xv.x * w0.x + xv.y * w0.y + xv.z * w0.z + xv.w * w0.w;
                p1 += xv.x * w1.x + xv.y * w1.y + xv.z * w1.z + xv.w * w1.w;
                p2 += xv.x * w2.x + xv.y * w2.y + xv.z * w2.z + xv.w * w2.w;
            }
            // 3-level butterfly within the 8-lane group (xor 1,2,4)
            #pragma unroll
            for (int off = 1; off <= 4; off <<= 1) {
                p0 += __shfl_xor(p0, off, 64);
                p1 += __shfl_xor(p1, off, 64);
                p2 += __shfl_xor(p2, off, 64);
            }
            const float af0 = p0 + sw[12];
            const float af1 = p1 + sw[13];
            const float af2 = p2 + sw[14];

            float dist[KK];
            #pragma unroll
            for (int k = 0; k < KK; ++k) {
                float da = af0 - sw[k * 3 + 0];
                float db = af1 - sw[k * 3 + 1];
                float dc = af2 - sw[k * 3 + 2];
                dist[k] = sqrtf(da * da + db * db + dc * dc);
            }
            float mn = fminf(fminf(dist[0], dist[1]), fminf(dist[2], dist[3]));
            float e[KK]; float esum = 0.f;
            #pragma unroll
            for (int k = 0; k < KK; ++k) { e[k] = __expf(mn - dist[k]); esum += e[k]; }
            const float einv = 1.0f / esum;

            float h[6];
            #pragma unroll
            for (int i6 = 0; i6 < 6; ++i6) {
                float v = af0 * sw[15 + i6] + af1 * sw[21 + i6]
                        + af2 * sw[27 + i6] + sw[33 + i6];
                h[i6] = fmaxf(v, 0.0f);
            }
            float logit[KK];
            #pragma unroll
            for (int k = 0; k < KK; ++k) {
                float v = sw[63 + k];
                #pragma unroll
                for (int i6 = 0; i6 < 6; ++i6) v += h[i6] * sw[39 + i6 * 4 + k];
                logit[k] = v + e[k] * einv;
            }
            float mx = fmaxf(fmaxf(logit[0], logit[1]), fmaxf(logit[2], logit[3]));
            float f0 = __expf(logit[0] - mx), f1 = __expf(logit[1] - mx);
            float f2 = __expf(logit[2] - mx), f3 = __expf(logit[3] - mx);
            const float finv = 1.0f / (f0 + f1 + f2 + f3);
            if (c == 0) {
                float4 fwv = {f0 * finv, f1 * finv, f2 * finv, f3 * finv};
                fw_lds[wave * GROUPS + g] = fwv;
            }
        }

        // ---- pooling phase: lane owns {4l..4l+3} and {256+4l..256+4l+3} ----
        {
            const float* xp = xbase + (size_t)s0 * DD;
            #pragma unroll 2
            for (int gg = 0; gg < GROUPS; ++gg) {
                const float* xr = xp + (size_t)gg * DD;
                float4 xlo = *(const float4*)(xr + 4 * lane);         // 1KB contig
                float4 xhi = *(const float4*)(xr + 256 + 4 * lane);   // 1KB contig
                float4 fwv = fw_lds[wave * GROUPS + gg];              // broadcast
                const float fk[KK] = {fwv.x, fwv.y, fwv.z, fwv.w};
                #pragma unroll
                for (int k = 0; k < KK; ++k) {
                    acc[k][0] += fk[k] * xlo.x;
                    acc[k][1] += fk[k] * xlo.y;
                    acc[k][2] += fk[k] * xlo.z;
                    acc[k][3] += fk[k] * xlo.w;
                    acc[k][4] += fk[k] * xhi.x;
                    acc[k][5] += fk[k] * xhi.y;
                    acc[k][6] += fk[k] * xhi.z;
                    acc[k][7] += fk[k] * xhi.w;
                }
            }
        }
    }

    // cross-wave combine via LDS float atomics (once per wave)
    #pragma unroll
    for (int k = 0; k < KK; ++k) {
        #pragma unroll
        for (int j = 0; j < 4; ++j)
            atomicAdd(&red[k * DD + 4 * lane + j], acc[k][j]);
        #pragma unroll
        for (int j = 0; j < 4; ++j)
            atomicAdd(&red[k * DD + 256 + 4 * lane + j], acc[k][4 + j]);
    }
    __syncthreads();

    float* pb = pooled + (size_t)b * (KK * DD);
    for (int cc2 = tid; cc2 < KK * DD; cc2 += 256)
        unsafeAtomicAdd(&pb[cc2], red[cc2]);
}

// out[b][col] = bout[col] + sum_j pooled[b][j] * Wout[j][col]
// R3-style grid (cc 2, b 32, jc 16) = 1024 blocks — measured faster than the
// 32-block b-inside variant (R4): parallelism beats Wout reuse here.
__global__ __launch_bounds__(256) void out_gemm_kernel(
    const float* __restrict__ pooled, const float* __restrict__ Wout,
    const float* __restrict__ bout, float* __restrict__ out)
{
    __shared__ float p_sh[128];
    const int tid = threadIdx.x;
    const int cc = blockIdx.x, b = blockIdx.y, jc = blockIdx.z;

    if (tid < 128) p_sh[tid] = pooled[b * 2048 + jc * 128 + tid];
    __syncthreads();

    const int col = cc * 256 + tid;
    const float* wp = Wout + (size_t)(jc * 128) * OUTD + col;
    float acc = 0.f;
    #pragma unroll 8
    for (int jj = 0; jj < 128; ++jj) {
        acc += p_sh[jj] * wp[(size_t)jj * OUTD];
    }
    if (jc == 0) acc += bout[col];
    unsafeAtomicAdd(&out[b * OUTD + col], acc);
}

extern "C" void kernel_launch(void* const* d_in, const int* in_sizes, int n_in,
                              void* d_out, int out_size, void* d_ws, size_t ws_size,
                              hipStream_t stream) {
    (void)in_sizes; (void)n_in; (void)out_size; (void)ws_size;
    const float* x       = (const float*)d_in[0];
    const float* centers = (const float*)d_in[1];
    const float* Wa      = (const float*)d_in[2];
    const float* ba      = (const float*)d_in[3];
    const float* Wh      = (const float*)d_in[4];
    const float* bh      = (const float*)d_in[5];
    const float* Wk      = (const float*)d_in[6];
    const float* bk      = (const float*)d_in[7];
    const float* Wout    = (const float*)d_in[8];
    const float* bout    = (const float*)d_in[9];
    float* out    = (float*)d_out;
    float* pooled = (float*)d_ws;   // B*K*D floats = 256 KB

    hipMemsetAsync(pooled, 0, (size_t)BB * KK * DD * sizeof(float), stream);
    hipMemsetAsync(out, 0, (size_t)BB * OUTD * sizeof(float), stream);

    fused_pool_kernel<<<dim3(NCHUNK, BB), 256, 0, stream>>>(
        x, centers, Wa, ba, Wh, bh, Wk, bk, pooled);
    out_gemm_kernel<<<dim3(2, BB, 16), 256, 0, stream>>>(pooled, Wout, bout, out);
}